// Round 1
// baseline (643.423 us; speedup 1.0000x reference)
//
#include <hip/hip_runtime.h>
#include <hip/hip_bf16.h>
#include <cstdint>

#define NB 16
#define NHh 112
#define NWw 112
#define NC 128
#define NL (NHh*NWw)      /* 12544 */
#define NHEADS 2
#define NDH 64
#define NHD 128
#define NK 4
#define ROWS (NB*NL)      /* 200704 */
#define PCHUNKS 49        /* NL/PCHUNKS = 256 rows per pooled block */

typedef unsigned short ushort_t;
typedef __attribute__((ext_vector_type(8))) short bf16x8;
typedef __attribute__((ext_vector_type(4))) float f32x4;

__device__ __forceinline__ float bf2f(unsigned int u){
  union { unsigned int i; float f; } v; v.i = u << 16; return v.f;
}
__device__ __forceinline__ ushort_t f2bf(float f){
  __hip_bfloat16 h = __float2bfloat16(f);
  return *reinterpret_cast<ushort_t*>(&h);
}

// ---------------- prep: qk[c][h] = (Wk . q)/8, scale_a = L * softplus(alpha) --------
__global__ void k_prep(const float* __restrict__ Wk, const float* __restrict__ q,
                       const float* __restrict__ alpha, float* __restrict__ qk,
                       float* __restrict__ scale_a){
  int t = threadIdx.x;
  if (t < NC*NHEADS){
    int c = t >> 1, h = t & 1;
    float s = 0.f;
    for (int d = 0; d < NDH; ++d) s += Wk[c*NHD + h*NDH + d] * q[h*NDH + d];
    qk[c*NHEADS + h] = s * 0.125f;   // fold 1/sqrt(dh)
  }
  if (t == 0){
    float a = alpha[0];
    float sp = (a > 20.f) ? a : log1pf(expf(a));
    *scale_a = (float)NL * sp;
  }
}

// ---------------- scores: one wave per row, scores[b,h,l] = x_row . qk[:,h] --------
template<typename XT>
__global__ void k_scores(const XT* __restrict__ x, const float* __restrict__ qk,
                         float* __restrict__ scores){
  __shared__ float sqk[NC*NHEADS];
  for (int i = threadIdx.x; i < NC*NHEADS; i += blockDim.x) sqk[i] = qk[i];
  __syncthreads();
  int lane = threadIdx.x & 63;
  int wid = blockIdx.x*(blockDim.x>>6) + (threadIdx.x>>6);
  int nw  = gridDim.x*(blockDim.x>>6);
  float q0a = sqk[(2*lane)*2+0],   q0b = sqk[(2*lane)*2+1];
  float q1a = sqk[(2*lane+1)*2+0], q1b = sqk[(2*lane+1)*2+1];
  for (int row = wid; row < ROWS; row += nw){
    float v0, v1;
    if constexpr (sizeof(XT) == 4){
      float2 v = *(const float2*)((const float*)x + (size_t)row*NC + 2*lane);
      v0 = v.x; v1 = v.y;
    } else {
      unsigned int u = *(const unsigned int*)((const ushort_t*)x + (size_t)row*NC + 2*lane);
      v0 = bf2f(u & 0xffffu); v1 = bf2f(u >> 16);
    }
    float p0 = v0*q0a + v1*q1a;
    float p1 = v0*q0b + v1*q1b;
    #pragma unroll
    for (int m = 32; m; m >>= 1){ p0 += __shfl_xor(p0, m); p1 += __shfl_xor(p1, m); }
    if (lane == 0){
      int b = row / NL, l = row % NL;
      scores[((size_t)b*NHEADS+0)*NL + l] = p0;
      scores[((size_t)b*NHEADS+1)*NL + l] = p1;
    }
  }
}

// ---------------- softmax over L per (b,h); in-place scores -> attn ----------------
__global__ void k_softmax(float* __restrict__ sc){
  __shared__ float sm[NL];
  __shared__ float red[4];
  float* s = sc + (size_t)blockIdx.x*NL;
  int t = threadIdx.x;
  float mx = -3.4e38f;
  for (int i = t; i < NL; i += 256){ float v = s[i]; sm[i] = v; mx = fmaxf(mx, v); }
  #pragma unroll
  for (int m = 32; m; m >>= 1) mx = fmaxf(mx, __shfl_xor(mx, m));
  if ((t & 63) == 0) red[t>>6] = mx;
  __syncthreads();
  mx = fmaxf(fmaxf(red[0], red[1]), fmaxf(red[2], red[3]));
  __syncthreads();
  float sum = 0.f;
  for (int i = t; i < NL; i += 256){ float e = expf(sm[i]-mx); sm[i] = e; sum += e; }
  #pragma unroll
  for (int m = 32; m; m >>= 1) sum += __shfl_xor(sum, m);
  if ((t & 63) == 0) red[t>>6] = sum;
  __syncthreads();
  sum = red[0]+red[1]+red[2]+red[3];
  float inv = 1.f/sum;
  for (int i = t; i < NL; i += 256) s[i] = sm[i]*inv;
}

// ---------------- pooled_x[b,h,c] = sum_l attn[b,h,l]*x[b,l,c] ---------------------
template<typename XT>
__global__ void k_pooled(const XT* __restrict__ x, const float* __restrict__ attn,
                         float* __restrict__ px){
  int b = blockIdx.x / PCHUNKS, chunk = blockIdx.x % PCHUNKS;
  int c = threadIdx.x & 127, half = threadIdx.x >> 7;
  const int rpc = NL/PCHUNKS;
  int l0 = chunk*rpc;
  float a0 = 0.f, a1 = 0.f;
  const float* at = attn + (size_t)b*NHEADS*NL;
  for (int i = half; i < rpc; i += 2){
    int l = l0 + i;
    float xv;
    if constexpr (sizeof(XT) == 4) xv = ((const float*)x)[((size_t)b*NL + l)*NC + c];
    else                           xv = bf2f(((const ushort_t*)x)[((size_t)b*NL + l)*NC + c]);
    a0 += at[l]*xv;
    a1 += at[NL+l]*xv;
  }
  atomicAdd(&px[(b*NHEADS+0)*NC + c], a0);
  atomicAdd(&px[(b*NHEADS+1)*NC + c], a1);
}

// -------- router tail: pooled->logits->softmax weights->combined W^T (bf16) --------
__global__ void k_combine(const float* __restrict__ px, const float* __restrict__ Wv,
                          const float* __restrict__ Wmlp, const float* __restrict__ Wb,
                          ushort_t* __restrict__ WT){
  int b = blockIdx.x, t = threadIdx.x;
  __shared__ float spx[NHEADS*NC];
  __shared__ float pooled[NHD];
  __shared__ float wts[NK];
  if (t < NHEADS*NC) spx[t] = px[b*NHEADS*NC + t];
  __syncthreads();
  if (t < NHD){
    int h = t >> 6, d = t & 63;
    float s = 0.f;
    for (int c = 0; c < NC; ++c) s += spx[h*NC + c] * Wv[c*NHD + h*NDH + d];
    pooled[t] = s;
  }
  __syncthreads();
  if (t < NK){
    float s = 0.f;
    for (int e = 0; e < NHD; ++e) s += pooled[e] * Wmlp[e*NK + t];
    wts[t] = s * (1.0f/1.5f);
  }
  __syncthreads();
  if (t == 0){
    float m = fmaxf(fmaxf(wts[0], wts[1]), fmaxf(wts[2], wts[3]));
    float e0 = expf(wts[0]-m), e1 = expf(wts[1]-m), e2 = expf(wts[2]-m), e3 = expf(wts[3]-m);
    float inv = 1.f/(e0+e1+e2+e3);
    wts[0] = e0*inv; wts[1] = e1*inv; wts[2] = e2*inv; wts[3] = e3*inv;
  }
  __syncthreads();
  float w0 = wts[0], w1 = wts[1], w2 = wts[2], w3 = wts[3];
  for (int idx = t; idx < NC*NHD; idx += blockDim.x){
    int d = idx >> 7, c = idx & 127;
    const float* wb = Wb + (size_t)c*NC + d;
    float v = w0*wb[0] + w1*wb[NC*NC] + w2*wb[2*NC*NC] + w3*wb[3*NC*NC];
    WT[(size_t)b*NC*NHD + d*NC + c] = f2bf(v);   // transposed: WT[d][c]
  }
}

// ---------------- x_out = (x*mod) @ Wcomb[b], per-batch, bf16 MFMA -----------------
template<typename XIN, typename XOUT>
__global__ void __launch_bounds__(256,2) k_gemm(const XIN* __restrict__ xin,
    const ushort_t* __restrict__ WT, const float* __restrict__ attn,
    const float* __restrict__ scale_a, XOUT* __restrict__ xout){
  __shared__ __align__(16) ushort_t lA[128*128];
  __shared__ __align__(16) ushort_t lB[128*128];
  const int nchunk = NL/128;   // 98
  int b = blockIdx.x / nchunk, chunk = blockIdx.x % nchunk;
  int l0 = chunk*128;
  int t = threadIdx.x;
  float sa = scale_a[0]*0.5f;  // fold head-mean 0.5
  const float* at = attn + (size_t)b*NHEADS*NL;

  // stage B = WT[b] (already transposed [d][c]), swizzled
  {
    const ushort_t* src = WT + (size_t)b*NC*NHD;
    #pragma unroll
    for (int i = 0; i < 8; ++i){
      int idx = i*2048 + t*8;
      int d = idx >> 7, c = idx & 127;
      uint4 v = *(const uint4*)(src + idx);
      int byo = (d*256 + c*2) ^ ((d & 7) << 4);
      *(uint4*)((char*)lB + byo) = v;
    }
  }
  // stage A = x rows * mod, convert to bf16, swizzled
  if constexpr (sizeof(XIN) == 4){
    const float* src = (const float*)xin + ((size_t)b*NL + l0)*NC;
    #pragma unroll
    for (int i = 0; i < 16; ++i){
      int idx = i*1024 + t*4;
      int row = idx >> 7, c = idx & 127;
      float4 v = *(const float4*)(src + idx);
      float mod = 1.f + (at[l0+row] + at[NL+l0+row])*sa;
      unsigned int p0 = (unsigned)f2bf(v.x*mod) | ((unsigned)f2bf(v.y*mod) << 16);
      unsigned int p1 = (unsigned)f2bf(v.z*mod) | ((unsigned)f2bf(v.w*mod) << 16);
      int byo = (row*256 + c*2) ^ ((row & 7) << 4);
      *(uint2*)((char*)lA + byo) = make_uint2(p0, p1);
    }
  } else {
    const ushort_t* src = (const ushort_t*)xin + ((size_t)b*NL + l0)*NC;
    #pragma unroll
    for (int i = 0; i < 8; ++i){
      int idx = i*2048 + t*8;
      int row = idx >> 7, c = idx & 127;
      uint4 v = *(const uint4*)(src + idx);
      float mod = 1.f + (at[l0+row] + at[NL+l0+row])*sa;
      unsigned int vv[4] = {v.x, v.y, v.z, v.w};
      unsigned int r[4];
      #pragma unroll
      for (int j = 0; j < 4; ++j){
        float lo = bf2f(vv[j] & 0xffffu)*mod, hi = bf2f(vv[j] >> 16)*mod;
        r[j] = (unsigned)f2bf(lo) | ((unsigned)f2bf(hi) << 16);
      }
      int byo = (row*256 + c*2) ^ ((row & 7) << 4);
      *(uint4*)((char*)lA + byo) = make_uint4(r[0], r[1], r[2], r[3]);
    }
  }
  __syncthreads();

  int lane = t & 63, wave = t >> 6;
  int trow = lane & 15, kg = lane >> 4;
  int r0 = wave*32;
  f32x4 acc[2][8];
  #pragma unroll
  for (int m = 0; m < 2; ++m)
    #pragma unroll
    for (int n = 0; n < 8; ++n) acc[m][n] = (f32x4){0.f,0.f,0.f,0.f};

  #pragma unroll
  for (int kk = 0; kk < 4; ++kk){
    int k = kk*32 + kg*8;
    int ra0 = r0 + trow, ra1 = r0 + 16 + trow;
    bf16x8 a0 = *(const bf16x8*)((const char*)lA + ((ra0*256 + k*2) ^ ((ra0 & 7) << 4)));
    bf16x8 a1 = *(const bf16x8*)((const char*)lA + ((ra1*256 + k*2) ^ ((ra1 & 7) << 4)));
    #pragma unroll
    for (int nt = 0; nt < 8; ++nt){
      int col = nt*16 + trow;
      bf16x8 bf = *(const bf16x8*)((const char*)lB + ((col*256 + k*2) ^ ((col & 7) << 4)));
      acc[0][nt] = __builtin_amdgcn_mfma_f32_16x16x32_bf16(a0, bf, acc[0][nt], 0, 0, 0);
      acc[1][nt] = __builtin_amdgcn_mfma_f32_16x16x32_bf16(a1, bf, acc[1][nt], 0, 0, 0);
    }
  }

  size_t base = ((size_t)b*NL + l0)*NC;
  #pragma unroll
  for (int m = 0; m < 2; ++m)
    #pragma unroll
    for (int nt = 0; nt < 8; ++nt)
      #pragma unroll
      for (int r = 0; r < 4; ++r){
        int row = r0 + m*16 + kg*4 + r;   // C layout: col=lane&15, row=(lane>>4)*4+reg
        int col = nt*16 + trow;
        float v = acc[m][nt][r];
        if constexpr (sizeof(XOUT) == 4) ((float*)xout)[base + (size_t)row*NC + col] = v;
        else                             ((ushort_t*)xout)[base + (size_t)row*NC + col] = f2bf(v);
      }
}

extern "C" void kernel_launch(void* const* d_in, const int* in_sizes, int n_in,
                              void* d_out, int out_size, void* d_ws, size_t ws_size,
                              hipStream_t stream){
  const float* x0   = (const float*)d_in[0];
  const float* Wk   = (const float*)d_in[1];
  const float* Wv   = (const float*)d_in[2];
  const float* q    = (const float*)d_in[3];
  const float* Wmlp = (const float*)d_in[4];
  const float* Wb   = (const float*)d_in[5];
  const float* alpha= (const float*)d_in[6];
  float* out = (float*)d_out;

  char* ws = (char*)d_ws;
  float* qk      = (float*)ws;                       // 256 f
  float* scale_a = qk + 256;                         // pad to 64
  float* scores  = qk + 320;                         // B*2*L f
  float* px      = scores + (size_t)NB*NHEADS*NL;    // B*2*C f
  ushort_t* WT   = (ushort_t*)(px + NB*NHEADS*NC);   // B*C*HD bf16
  size_t fixed   = (size_t)((char*)(WT + (size_t)NB*NC*NHD) - ws);
  size_t xoff    = (fixed + 255) & ~(size_t)255;
  ushort_t* xb   = (ushort_t*)(ws + xoff);
  bool big = ws_size >= xoff + (size_t)ROWS*NC*2;

  k_prep<<<1, 256, 0, stream>>>(Wk, q, alpha, qk, scale_a);

  for (int step = 0; step < 3; ++step){
    const void* xi; void* xo; bool xi_bf, xo_bf;
    if (big){
      if (step == 0){ xi = x0;  xi_bf = false; xo = xb;  xo_bf = true;  }
      else if (step == 1){ xi = xb; xi_bf = true; xo = xb; xo_bf = true; }
      else { xi = xb; xi_bf = true; xo = out; xo_bf = false; }
    } else {
      xi = (step == 0) ? (const void*)x0 : (const void*)out;
      xi_bf = false; xo = out; xo_bf = false;
    }

    if (xi_bf) k_scores<ushort_t><<<1568, 256, 0, stream>>>((const ushort_t*)xi, qk, scores);
    else       k_scores<float   ><<<1568, 256, 0, stream>>>((const float*)xi, qk, scores);

    k_softmax<<<NB*NHEADS, 256, 0, stream>>>(scores);

    hipMemsetAsync(px, 0, (size_t)NB*NHEADS*NC*sizeof(float), stream);

    if (xi_bf) k_pooled<ushort_t><<<NB*PCHUNKS, 256, 0, stream>>>((const ushort_t*)xi, scores, px);
    else       k_pooled<float   ><<<NB*PCHUNKS, 256, 0, stream>>>((const float*)xi, scores, px);

    k_combine<<<NB, 256, 0, stream>>>(px, Wv, Wmlp, Wb, WT);

    dim3 g(NB*(NL/128));
    if (xi_bf){
      if (xo_bf) k_gemm<ushort_t, ushort_t><<<g, 256, 0, stream>>>((const ushort_t*)xi, WT, scores, scale_a, (ushort_t*)xo);
      else       k_gemm<ushort_t, float   ><<<g, 256, 0, stream>>>((const ushort_t*)xi, WT, scores, scale_a, (float*)xo);
    } else {
      if (xo_bf) k_gemm<float, ushort_t><<<g, 256, 0, stream>>>((const float*)xi, WT, scores, scale_a, (ushort_t*)xo);
      else       k_gemm<float, float   ><<<g, 256, 0, stream>>>((const float*)xi, WT, scores, scale_a, (float*)xo);
    }
  }
}

// Round 2
// 453.185 us; speedup vs baseline: 1.4198x; 1.4198x over previous
//
#include <hip/hip_runtime.h>
#include <hip/hip_bf16.h>
#include <cstdint>

#define NB 16
#define NC 128
#define NL 12544
#define NHD 128
#define NK 4
#define ROWS (NB*NL)
#define PCH 49        /* chunks per batch */
#define CHROWS 256    /* rows per chunk */

typedef unsigned short ushort_t;
typedef __attribute__((ext_vector_type(8))) short bf16x8;
typedef __attribute__((ext_vector_type(4))) float f32x4;

__device__ __forceinline__ float bf2f(unsigned int u){
  union { unsigned int i; float f; } v; v.i = u << 16; return v.f;
}
__device__ __forceinline__ ushort_t f2bf(float f){
  __hip_bfloat16 h = __float2bfloat16(f);
  return *reinterpret_cast<ushort_t*>(&h);
}

// ---------------- prep: qk[c][h] = (Wk . q)/8, scale_a = L * softplus(alpha) -------
__global__ void k_prep(const float* __restrict__ Wk, const float* __restrict__ q,
                       const float* __restrict__ alpha, float* __restrict__ qk,
                       float* __restrict__ scale_a){
  int t = threadIdx.x;
  if (t < NC*2){
    int c = t >> 1, h = t & 1;
    float s = 0.f;
    for (int d = 0; d < 64; ++d) s += Wk[c*NHD + h*64 + d] * q[h*64 + d];
    qk[c*2 + h] = s * 0.125f;
  }
  if (t == 0){
    float a = alpha[0];
    float sp = (a > 20.f) ? a : log1pf(expf(a));
    *scale_a = (float)NL * sp;
  }
}

// ------- fused pass1: x chunk -> LDS; scores (MFMA); block-local online softmax;
// ------- partial pooled P = sum(e * x); writes raw scores + {m,S,P} partials -------
template<typename XT>
__global__ void __launch_bounds__(256,2) k_pass1(const XT* __restrict__ x,
    const float* __restrict__ qk, float* __restrict__ sraw,
    float* __restrict__ pm, float* __restrict__ pS, float* __restrict__ pP){
  __shared__ __align__(16) ushort_t xs[CHROWS*NC];
  __shared__ float sh0[CHROWS], sh1[CHROWS];
  __shared__ float red[8];
  int b = blockIdx.x / PCH, chunk = blockIdx.x % PCH;
  int l0 = chunk*CHROWS;
  int t = threadIdx.x, lane = t & 63, wave = t >> 6;
  int hi = lane >> 4, n16 = lane & 15;

  // ---- stage x chunk -> LDS bf16, XOR-swizzled ----
  if constexpr (sizeof(XT) == 4){
    const float* src = (const float*)x + ((size_t)b*NL + l0)*NC;
    #pragma unroll
    for (int i = 0; i < 16; ++i){
      int idx = i*2048 + t*8;
      int row = idx >> 7;
      float4 v0 = *(const float4*)(src + idx);
      float4 v1 = *(const float4*)(src + idx + 4);
      uint4 p;
      p.x = (unsigned)f2bf(v0.x) | ((unsigned)f2bf(v0.y) << 16);
      p.y = (unsigned)f2bf(v0.z) | ((unsigned)f2bf(v0.w) << 16);
      p.z = (unsigned)f2bf(v1.x) | ((unsigned)f2bf(v1.y) << 16);
      p.w = (unsigned)f2bf(v1.z) | ((unsigned)f2bf(v1.w) << 16);
      *(uint4*)((char*)xs + ((idx*2) ^ ((row & 7) << 4))) = p;
    }
  } else {
    const ushort_t* src = (const ushort_t*)x + ((size_t)b*NL + l0)*NC;
    #pragma unroll
    for (int i = 0; i < 16; ++i){
      int idx = i*2048 + t*8;
      int row = idx >> 7;
      uint4 v = *(const uint4*)(src + idx);
      *(uint4*)((char*)xs + ((idx*2) ^ ((row & 7) << 4))) = v;
    }
  }

  // ---- qk B-fragments (bf16), n=lane&15 -> head (only n<2 live) ----
  bf16x8 qfv[4];
  #pragma unroll
  for (int kk = 0; kk < 4; ++kk)
    #pragma unroll
    for (int j = 0; j < 8; ++j){
      int k = kk*32 + hi*8 + j;
      qfv[kk][j] = (n16 < 2) ? (short)f2bf(qk[k*2 + n16]) : (short)0;
    }
  __syncthreads();

  // ---- scores via MFMA: s[row][h] = x_row . qk[:,h]; wave owns 4 row-tiles ----
  #pragma unroll
  for (int rt4 = 0; rt4 < 4; ++rt4){
    int rt = wave*4 + rt4;
    f32x4 acc = (f32x4){0.f,0.f,0.f,0.f};
    #pragma unroll
    for (int kk = 0; kk < 4; ++kk){
      int row = rt*16 + n16;
      int k = kk*32 + hi*8;
      bf16x8 a = *(const bf16x8*)((const char*)xs + ((row*256 + k*2) ^ ((row & 7) << 4)));
      acc = __builtin_amdgcn_mfma_f32_16x16x32_bf16(a, qfv[kk], acc, 0, 0, 0);
    }
    if (n16 < 2){
      float* dst = n16 ? sh1 : sh0;
      #pragma unroll
      for (int r = 0; r < 4; ++r) dst[rt*16 + hi*4 + r] = acc[r];
    }
  }
  __syncthreads();

  // ---- raw score write + block max ----
  float s0 = sh0[t], s1 = sh1[t];
  sraw[((size_t)b*2 + 0)*NL + l0 + t] = s0;
  sraw[((size_t)b*2 + 1)*NL + l0 + t] = s1;
  float m0 = s0, m1 = s1;
  #pragma unroll
  for (int m = 32; m; m >>= 1){ m0 = fmaxf(m0, __shfl_xor(m0, m)); m1 = fmaxf(m1, __shfl_xor(m1, m)); }
  if (lane == 0){ red[wave] = m0; red[4+wave] = m1; }
  __syncthreads();
  m0 = fmaxf(fmaxf(red[0], red[1]), fmaxf(red[2], red[3]));
  m1 = fmaxf(fmaxf(red[4], red[5]), fmaxf(red[6], red[7]));
  float e0 = __expf(s0 - m0), e1 = __expf(s1 - m1);
  // ---- block sums ----
  float t0 = e0, t1 = e1;
  #pragma unroll
  for (int m = 32; m; m >>= 1){ t0 += __shfl_xor(t0, m); t1 += __shfl_xor(t1, m); }
  __syncthreads();
  if (lane == 0){ red[wave] = t0; red[4+wave] = t1; }
  sh0[t] = e0; sh1[t] = e1;
  __syncthreads();
  if (t == 0){
    pm[(b*2+0)*PCH + chunk] = m0;  pm[(b*2+1)*PCH + chunk] = m1;
    pS[(b*2+0)*PCH + chunk] = red[0]+red[1]+red[2]+red[3];
    pS[(b*2+1)*PCH + chunk] = red[4]+red[5]+red[6]+red[7];
  }

  // ---- partial pooled: P[h][c] = sum_l e_h[l] * x[l][c] ----
  int h = t >> 7, half = (t >> 6) & 1, cp = t & 63;
  const float* es = h ? sh1 : sh0;
  float a0 = 0.f, a1 = 0.f;
  #pragma unroll 4
  for (int i = 0; i < 128; ++i){
    int l = half*128 + i;
    float e = es[l];
    unsigned u = *(const unsigned*)((const char*)xs + ((l*256 + 4*cp) ^ ((l & 7) << 4)));
    a0 += e * bf2f(u & 0xffffu);
    a1 += e * bf2f(u >> 16);
  }
  __syncthreads();
  if (half){ sh0[h*128 + cp*2] = a0; sh0[h*128 + cp*2 + 1] = a1; }
  __syncthreads();
  if (!half){
    a0 += sh0[h*128 + cp*2];
    a1 += sh0[h*128 + cp*2 + 1];
    float2 w; w.x = a0; w.y = a1;
    *(float2*)&pP[(((size_t)b*PCH + chunk)*2 + h)*NC + 2*cp] = w;
  }
}

// -------- merge chunks (LSE), router tail, combined W^T (bf16), export {m,1/S} ----
__global__ void k_combine(const float* __restrict__ pm, const float* __restrict__ pS,
    const float* __restrict__ pP, const float* __restrict__ Wv,
    const float* __restrict__ Wmlp, const float* __restrict__ Wb,
    ushort_t* __restrict__ WT, float* __restrict__ amS){
  int b = blockIdx.x, t = threadIdx.x;
  __shared__ float w49[2][PCH];
  __shared__ float pxs[2][NC];
  __shared__ float vpool[NHD];
  __shared__ float wts[NK];
  __shared__ float mS[4];
  if (t < 2){
    float m = -3.4e38f;
    for (int j = 0; j < PCH; ++j) m = fmaxf(m, pm[(b*2+t)*PCH + j]);
    float S = 0.f;
    for (int j = 0; j < PCH; ++j) S += pS[(b*2+t)*PCH + j] * __expf(pm[(b*2+t)*PCH + j] - m);
    float iS = 1.f/S;
    mS[t] = m; mS[2+t] = iS;
    amS[(b*2+t)*2 + 0] = m; amS[(b*2+t)*2 + 1] = iS;
  }
  __syncthreads();
  if (t < 2*PCH){ int h = t/PCH, j = t%PCH; w49[h][j] = __expf(pm[(b*2+h)*PCH + j] - mS[h]); }
  __syncthreads();
  {
    int h = t >> 7, c = t & 127;
    float s = 0.f;
    for (int j = 0; j < PCH; ++j) s += pP[(((size_t)b*PCH + j)*2 + h)*NC + c] * w49[h][j];
    pxs[h][c] = s * mS[2+h];
  }
  __syncthreads();
  if (t < NHD){
    int h = t >> 6, d = t & 63;
    float s = 0.f;
    for (int c = 0; c < NC; ++c) s += pxs[h][c] * Wv[c*NHD + h*64 + d];
    vpool[t] = s;
  }
  __syncthreads();
  if (t < NK){
    float s = 0.f;
    for (int e = 0; e < NHD; ++e) s += vpool[e] * Wmlp[e*NK + t];
    wts[t] = s * (1.0f/1.5f);
  }
  __syncthreads();
  if (t == 0){
    float m = fmaxf(fmaxf(wts[0], wts[1]), fmaxf(wts[2], wts[3]));
    float e0 = __expf(wts[0]-m), e1 = __expf(wts[1]-m), e2 = __expf(wts[2]-m), e3 = __expf(wts[3]-m);
    float inv = 1.f/(e0+e1+e2+e3);
    wts[0] = e0*inv; wts[1] = e1*inv; wts[2] = e2*inv; wts[3] = e3*inv;
  }
  __syncthreads();
  float w0 = wts[0], w1 = wts[1], w2 = wts[2], w3 = wts[3];
  for (int idx = t; idx < NC*NHD; idx += 256){
    int d = idx >> 7, c = idx & 127;
    const float* wb = Wb + (size_t)c*NC + d;
    float v = w0*wb[0] + w1*wb[NC*NC] + w2*wb[2*NC*NC] + w3*wb[3*NC*NC];
    WT[(size_t)b*NC*NHD + d*NC + c] = f2bf(v);   // transposed: WT[d][c]
  }
}

// ---------------- x_out = (x*mod) @ Wcomb[b], per-batch, bf16 MFMA -----------------
template<typename XIN, typename XOUT>
__global__ void __launch_bounds__(256,2) k_gemm(const XIN* __restrict__ xin,
    const ushort_t* __restrict__ WT, const float* __restrict__ sraw,
    const float* __restrict__ amS, const float* __restrict__ scale_a,
    XOUT* __restrict__ xout){
  __shared__ __align__(16) ushort_t lA[128*128];
  __shared__ __align__(16) ushort_t lB[128*128];
  const int nchunk = NL/128;   // 98
  int b = blockIdx.x / nchunk, chunk = blockIdx.x % nchunk;
  int l0 = chunk*128;
  int t = threadIdx.x;
  float sa = scale_a[0]*0.5f;  // fold head-mean 0.5
  float am0 = amS[(b*2+0)*2+0], ai0 = amS[(b*2+0)*2+1];
  float am1 = amS[(b*2+1)*2+0], ai1 = amS[(b*2+1)*2+1];
  const float* s0p = sraw + ((size_t)b*2 + 0)*NL + l0;
  const float* s1p = sraw + ((size_t)b*2 + 1)*NL + l0;

  // stage B = WT[b] (already transposed [d][c]), swizzled
  {
    const ushort_t* src = WT + (size_t)b*NC*NHD;
    #pragma unroll
    for (int i = 0; i < 8; ++i){
      int idx = i*2048 + t*8;
      int d = idx >> 7, c = idx & 127;
      uint4 v = *(const uint4*)(src + idx);
      int byo = (d*256 + c*2) ^ ((d & 7) << 4);
      *(uint4*)((char*)lB + byo) = v;
    }
  }
  // stage A = x rows * mod, convert to bf16, swizzled
  if constexpr (sizeof(XIN) == 4){
    const float* src = (const float*)xin + ((size_t)b*NL + l0)*NC;
    #pragma unroll
    for (int i = 0; i < 16; ++i){
      int idx = i*1024 + t*4;
      int row = idx >> 7, c = idx & 127;
      float4 v = *(const float4*)(src + idx);
      float mod = 1.f + sa*(__expf(s0p[row]-am0)*ai0 + __expf(s1p[row]-am1)*ai1);
      unsigned int p0 = (unsigned)f2bf(v.x*mod) | ((unsigned)f2bf(v.y*mod) << 16);
      unsigned int p1 = (unsigned)f2bf(v.z*mod) | ((unsigned)f2bf(v.w*mod) << 16);
      int byo = (row*256 + c*2) ^ ((row & 7) << 4);
      *(uint2*)((char*)lA + byo) = make_uint2(p0, p1);
    }
  } else {
    const ushort_t* src = (const ushort_t*)xin + ((size_t)b*NL + l0)*NC;
    #pragma unroll
    for (int i = 0; i < 8; ++i){
      int idx = i*2048 + t*8;
      int row = idx >> 7, c = idx & 127;
      uint4 v = *(const uint4*)(src + idx);
      float mod = 1.f + sa*(__expf(s0p[row]-am0)*ai0 + __expf(s1p[row]-am1)*ai1);
      unsigned int vv[4] = {v.x, v.y, v.z, v.w};
      unsigned int r[4];
      #pragma unroll
      for (int j = 0; j < 4; ++j){
        float lo = bf2f(vv[j] & 0xffffu)*mod, hi2 = bf2f(vv[j] >> 16)*mod;
        r[j] = (unsigned)f2bf(lo) | ((unsigned)f2bf(hi2) << 16);
      }
      int byo = (row*256 + c*2) ^ ((row & 7) << 4);
      *(uint4*)((char*)lA + byo) = make_uint4(r[0], r[1], r[2], r[3]);
    }
  }
  __syncthreads();

  int lane = t & 63, wave = t >> 6;
  int trow = lane & 15, kg = lane >> 4;
  int r0 = wave*32;
  f32x4 acc[2][8];
  #pragma unroll
  for (int m = 0; m < 2; ++m)
    #pragma unroll
    for (int n = 0; n < 8; ++n) acc[m][n] = (f32x4){0.f,0.f,0.f,0.f};

  #pragma unroll
  for (int kk = 0; kk < 4; ++kk){
    int k = kk*32 + kg*8;
    int ra0 = r0 + trow, ra1 = r0 + 16 + trow;
    bf16x8 a0 = *(const bf16x8*)((const char*)lA + ((ra0*256 + k*2) ^ ((ra0 & 7) << 4)));
    bf16x8 a1 = *(const bf16x8*)((const char*)lA + ((ra1*256 + k*2) ^ ((ra1 & 7) << 4)));
    #pragma unroll
    for (int nt = 0; nt < 8; ++nt){
      int col = nt*16 + trow;
      bf16x8 bf = *(const bf16x8*)((const char*)lB + ((col*256 + k*2) ^ ((col & 7) << 4)));
      acc[0][nt] = __builtin_amdgcn_mfma_f32_16x16x32_bf16(a0, bf, acc[0][nt], 0, 0, 0);
      acc[1][nt] = __builtin_amdgcn_mfma_f32_16x16x32_bf16(a1, bf, acc[1][nt], 0, 0, 0);
    }
  }

  size_t base = ((size_t)b*NL + l0)*NC;
  #pragma unroll
  for (int m = 0; m < 2; ++m)
    #pragma unroll
    for (int nt = 0; nt < 8; ++nt)
      #pragma unroll
      for (int r = 0; r < 4; ++r){
        int row = r0 + m*16 + kg*4 + r;   // C layout: col=lane&15, row=(lane>>4)*4+reg
        int col = nt*16 + trow;
        float v = acc[m][nt][r];
        if constexpr (sizeof(XOUT) == 4) ((float*)xout)[base + (size_t)row*NC + col] = v;
        else                             ((ushort_t*)xout)[base + (size_t)row*NC + col] = f2bf(v);
      }
}

extern "C" void kernel_launch(void* const* d_in, const int* in_sizes, int n_in,
                              void* d_out, int out_size, void* d_ws, size_t ws_size,
                              hipStream_t stream){
  const float* x0   = (const float*)d_in[0];
  const float* Wk   = (const float*)d_in[1];
  const float* Wv   = (const float*)d_in[2];
  const float* q    = (const float*)d_in[3];
  const float* Wmlp = (const float*)d_in[4];
  const float* Wb   = (const float*)d_in[5];
  const float* alpha= (const float*)d_in[6];
  float* out = (float*)d_out;

  char* ws = (char*)d_ws;
  float* qk      = (float*)ws;                        // 256 f (+pad)
  float* scale_a = qk + 256;
  float* sraw    = qk + 320;                          // B*2*L f
  float* pm      = sraw + (size_t)NB*2*NL;            // B*2*49 f
  float* pS      = pm + NB*2*PCH;
  float* pP      = pS + NB*2*PCH;                     // B*49*2*128 f
  float* amS     = pP + (size_t)NB*PCH*2*NC;          // B*2*2 f
  ushort_t* WT   = (ushort_t*)(amS + NB*4);           // B*128*128 bf16
  char* endfixed = (char*)(WT + (size_t)NB*NC*NHD);
  size_t xoff    = ((size_t)(endfixed - ws) + 255) & ~(size_t)255;
  ushort_t* xb   = (ushort_t*)(ws + xoff);
  bool big = ws_size >= xoff + (size_t)ROWS*NC*2;

  k_prep<<<1, 256, 0, stream>>>(Wk, q, alpha, qk, scale_a);

  for (int step = 0; step < 3; ++step){
    const void* xi; void* xo; bool xi_bf, xo_bf;
    if (big){
      if (step == 0){ xi = x0;  xi_bf = false; xo = xb;  xo_bf = true;  }
      else if (step == 1){ xi = xb; xi_bf = true; xo = xb; xo_bf = true; }
      else { xi = xb; xi_bf = true; xo = out; xo_bf = false; }
    } else {
      xi = (step == 0) ? (const void*)x0 : (const void*)out;
      xi_bf = false; xo = out; xo_bf = false;
    }

    if (xi_bf) k_pass1<ushort_t><<<NB*PCH, 256, 0, stream>>>((const ushort_t*)xi, qk, sraw, pm, pS, pP);
    else       k_pass1<float   ><<<NB*PCH, 256, 0, stream>>>((const float*)xi, qk, sraw, pm, pS, pP);

    k_combine<<<NB, 256, 0, stream>>>(pm, pS, pP, Wv, Wmlp, Wb, WT, amS);

    dim3 g(NB*(NL/128));
    if (xi_bf){
      if (xo_bf) k_gemm<ushort_t, ushort_t><<<g, 256, 0, stream>>>((const ushort_t*)xi, WT, sraw, amS, scale_a, (ushort_t*)xo);
      else       k_gemm<ushort_t, float   ><<<g, 256, 0, stream>>>((const ushort_t*)xi, WT, sraw, amS, scale_a, (float*)xo);
    } else {
      if (xo_bf) k_gemm<float, ushort_t><<<g, 256, 0, stream>>>((const float*)xi, WT, sraw, amS, scale_a, (ushort_t*)xo);
      else       k_gemm<float, float   ><<<g, 256, 0, stream>>>((const float*)xi, WT, sraw, amS, scale_a, (float*)xo);
    }
  }
}

// Round 3
// 388.093 us; speedup vs baseline: 1.6579x; 1.1677x over previous
//
#include <hip/hip_runtime.h>
#include <hip/hip_bf16.h>
#include <cstdint>

#define NB 16
#define NC 128
#define NL 12544
#define NHD 128
#define NK 4
#define ROWS (NB*NL)
#define CH 128          /* rows per chunk */
#define PCH2 98         /* NL/CH chunks per batch */

typedef unsigned short ushort_t;
typedef __attribute__((ext_vector_type(8))) short bf16x8;
typedef __attribute__((ext_vector_type(4))) float f32x4;

__device__ __forceinline__ float bf2f(unsigned int u){
  union { unsigned int i; float f; } v; v.i = u << 16; return v.f;
}
__device__ __forceinline__ ushort_t f2bf(float f){
  __hip_bfloat16 h = __float2bfloat16(f);
  return *reinterpret_cast<ushort_t*>(&h);
}

// ---------------- prep: qk[c][h] = (Wk . q)/8, scale_a = L * softplus(alpha) -------
__global__ void k_prep(const float* __restrict__ Wk, const float* __restrict__ q,
                       const float* __restrict__ alpha, float* __restrict__ qk,
                       float* __restrict__ scale_a){
  int t = threadIdx.x;
  if (t < NC*2){
    int c = t >> 1, h = t & 1;
    float s = 0.f;
    for (int d = 0; d < 64; ++d) s += Wk[c*NHD + h*64 + d] * q[h*64 + d];
    qk[c*2 + h] = s * 0.125f;
  }
  if (t == 0){
    float a = alpha[0];
    float sp = (a > 20.f) ? a : log1pf(expf(a));
    *scale_a = (float)NL * sp;
  }
}

// ------- pass1 (step-0 only): x0 chunk -> LDS bf16; scores (MFMA); block-local
// ------- softmax stats; partial pooled; writes sraw + {m,S,P} chunk partials ------
__global__ void __launch_bounds__(256,4) k_pass1(const float* __restrict__ x,
    const float* __restrict__ qk, float* __restrict__ sraw,
    float* __restrict__ pm, float* __restrict__ pS, float* __restrict__ pP){
  __shared__ __align__(16) ushort_t xs[CH*NC];
  __shared__ float shs0[CH], shs1[CH];
  __shared__ float red[8];
  __shared__ float pmerge[256];
  int wg = ((blockIdx.x & 7) * 196) + (blockIdx.x >> 3);
  int b = wg / PCH2, chunk = wg % PCH2;
  int l0 = chunk*CH;
  int t = threadIdx.x, lane = t & 63, wave = t >> 6;
  int hi = lane >> 4, n16 = lane & 15;

  // stage fp32 -> bf16, XOR-swizzled
  {
    const float* src = x + ((size_t)b*NL + l0)*NC;
    #pragma unroll
    for (int i = 0; i < 16; ++i){
      int idx = i*1024 + t*4;
      int row = idx >> 7;
      float4 v = *(const float4*)(src + idx);
      unsigned p0 = (unsigned)f2bf(v.x) | ((unsigned)f2bf(v.y) << 16);
      unsigned p1 = (unsigned)f2bf(v.z) | ((unsigned)f2bf(v.w) << 16);
      *(uint2*)((char*)xs + ((idx*2) ^ ((row & 7) << 4))) = make_uint2(p0, p1);
    }
  }
  // qk B-fragments
  bf16x8 qfv[4];
  #pragma unroll
  for (int kk = 0; kk < 4; ++kk)
    #pragma unroll
    for (int j = 0; j < 8; ++j){
      int k = kk*32 + hi*8 + j;
      qfv[kk][j] = (n16 < 2) ? (short)f2bf(qk[k*2 + n16]) : (short)0;
    }
  __syncthreads();

  // scores: 8 row-tiles, wave handles 2
  #pragma unroll
  for (int rt2 = 0; rt2 < 2; ++rt2){
    int rt = wave*2 + rt2;
    f32x4 acc = (f32x4){0.f,0.f,0.f,0.f};
    #pragma unroll
    for (int kk = 0; kk < 4; ++kk){
      int row = rt*16 + n16;
      int k = kk*32 + hi*8;
      bf16x8 a = *(const bf16x8*)((const char*)xs + ((row*256 + k*2) ^ ((row & 7) << 4)));
      acc = __builtin_amdgcn_mfma_f32_16x16x32_bf16(a, qfv[kk], acc, 0, 0, 0);
    }
    if (n16 < 2){
      float* dst = n16 ? shs1 : shs0;
      #pragma unroll
      for (int r = 0; r < 4; ++r) dst[rt*16 + hi*4 + r] = acc[r];
    }
  }
  __syncthreads();

  // block softmax stats over 128 rows
  float s0 = -3.4e38f, s1 = -3.4e38f;
  if (t < 128){
    s0 = shs0[t]; s1 = shs1[t];
    sraw[((size_t)b*2+0)*NL + l0 + t] = s0;
    sraw[((size_t)b*2+1)*NL + l0 + t] = s1;
  }
  float m0 = s0, m1 = s1;
  #pragma unroll
  for (int mk = 32; mk; mk >>= 1){ m0 = fmaxf(m0, __shfl_xor(m0, mk)); m1 = fmaxf(m1, __shfl_xor(m1, mk)); }
  if (lane == 0 && wave < 2){ red[wave] = m0; red[2+wave] = m1; }
  __syncthreads();
  float M0 = fmaxf(red[0], red[1]), M1 = fmaxf(red[2], red[3]);
  float e0 = 0.f, e1 = 0.f;
  if (t < 128){ e0 = __expf(s0 - M0); e1 = __expf(s1 - M1); shs0[t] = e0; shs1[t] = e1; }
  float t0 = e0, t1 = e1;
  #pragma unroll
  for (int mk = 32; mk; mk >>= 1){ t0 += __shfl_xor(t0, mk); t1 += __shfl_xor(t1, mk); }
  if (lane == 0 && wave < 2){ red[4+wave] = t0; red[6+wave] = t1; }
  __syncthreads();
  if (t == 0){
    pm[(b*2+0)*PCH2 + chunk] = M0; pm[(b*2+1)*PCH2 + chunk] = M1;
    pS[(b*2+0)*PCH2 + chunk] = red[4]+red[5];
    pS[(b*2+1)*PCH2 + chunk] = red[6]+red[7];
  }

  // partial pooled: P[h][c] = sum_l e_h[l]*x[l][c]
  int h = t >> 7, half = (t >> 6) & 1, cp = t & 63;
  const float* es = h ? shs1 : shs0;
  float a0 = 0.f, a1 = 0.f;
  #pragma unroll 4
  for (int i = 0; i < 64; ++i){
    int l = half*64 + i;
    float e = es[l];
    unsigned u = *(const unsigned*)((const char*)xs + ((l*256 + 4*cp) ^ ((l & 7) << 4)));
    a0 += e * bf2f(u & 0xffffu);
    a1 += e * bf2f(u >> 16);
  }
  __syncthreads();
  if (half){ pmerge[h*128 + cp*2] = a0; pmerge[h*128 + cp*2 + 1] = a1; }
  __syncthreads();
  if (!half){
    a0 += pmerge[h*128 + cp*2];
    a1 += pmerge[h*128 + cp*2 + 1];
    float2 w; w.x = a0; w.y = a1;
    *(float2*)&pP[(((size_t)b*PCH2 + chunk)*2 + h)*NC + 2*cp] = w;
  }
}

// -------- merge chunks (LSE), router tail, combined W^T (bf16), export {m,1/S} ----
__global__ void k_combine(const float* __restrict__ pm, const float* __restrict__ pS,
    const float* __restrict__ pP, const float* __restrict__ Wv,
    const float* __restrict__ Wmlp, const float* __restrict__ Wb,
    ushort_t* __restrict__ WT, float* __restrict__ amS){
  int b = blockIdx.x, t = threadIdx.x, lane = t & 63, wave = t >> 6;
  __shared__ float w98[2][PCH2];
  __shared__ float pxs[2][NC];
  __shared__ float vpool[NHD];
  __shared__ float wts[NK];
  __shared__ float mSh[4];
  __shared__ float wcomb[NC*129];   // [c][d], padded

  if (wave < 2){
    int h = wave;
    const float* pmh = pm + (b*2+h)*PCH2;
    const float* pSh = pS + (b*2+h)*PCH2;
    float m = -3.4e38f;
    for (int j = lane; j < PCH2; j += 64) m = fmaxf(m, pmh[j]);
    #pragma unroll
    for (int mk = 32; mk; mk >>= 1) m = fmaxf(m, __shfl_xor(m, mk));
    float S = 0.f;
    for (int j = lane; j < PCH2; j += 64) S += pSh[j] * __expf(pmh[j] - m);
    #pragma unroll
    for (int mk = 32; mk; mk >>= 1) S += __shfl_xor(S, mk);
    for (int j = lane; j < PCH2; j += 64) w98[h][j] = __expf(pmh[j] - m);
    if (lane == 0){
      float iS = 1.f/S;
      mSh[h] = m; mSh[2+h] = iS;
      amS[(b*2+h)*2 + 0] = m; amS[(b*2+h)*2 + 1] = iS;
    }
  }
  __syncthreads();
  {
    int h = t >> 7, c = t & 127;
    float s = 0.f;
    #pragma unroll 2
    for (int j = 0; j < PCH2; ++j) s += pP[(((size_t)b*PCH2 + j)*2 + h)*NC + c] * w98[h][j];
    pxs[h][c] = s * mSh[2+h];
  }
  __syncthreads();
  if (t < NHD){
    int h = t >> 6, d = t & 63;
    float s = 0.f;
    for (int c = 0; c < NC; ++c) s += pxs[h][c] * Wv[c*NHD + h*64 + d];
    vpool[t] = s;
  }
  __syncthreads();
  if (t < NK){
    float s = 0.f;
    for (int e = 0; e < NHD; ++e) s += vpool[e] * Wmlp[e*NK + t];
    wts[t] = s * (1.0f/1.5f);
  }
  __syncthreads();
  if (t == 0){
    float m = fmaxf(fmaxf(wts[0], wts[1]), fmaxf(wts[2], wts[3]));
    float e0 = __expf(wts[0]-m), e1 = __expf(wts[1]-m), e2 = __expf(wts[2]-m), e3 = __expf(wts[3]-m);
    float inv = 1.f/(e0+e1+e2+e3);
    wts[0] = e0*inv; wts[1] = e1*inv; wts[2] = e2*inv; wts[3] = e3*inv;
  }
  __syncthreads();
  float w0 = wts[0], w1 = wts[1], w2 = wts[2], w3 = wts[3];
  // combined W: coalesced Wb reads (d contiguous) -> LDS [c][d]
  for (int idx = t; idx < NC*NC; idx += 256){
    int c = idx >> 7, d = idx & 127;
    const float* wb = Wb + (size_t)c*NC + d;
    wcomb[c*129 + d] = w0*wb[0] + w1*wb[NC*NC] + w2*wb[2*NC*NC] + w3*wb[3*NC*NC];
  }
  __syncthreads();
  // WT[d][c] write, coalesced in c; LDS read stride 129 -> conflict-free
  for (int idx = t; idx < NC*NHD; idx += 256){
    int d = idx >> 7, c = idx & 127;
    WT[(size_t)b*NC*NHD + d*NC + c] = f2bf(wcomb[c*129 + d]);
  }
}

// ------- gemm: x_out = (x*mod) @ Wcomb[b]; epilogue computes NEXT step's router
// ------- stats (scores/max/sum/partial-pooled) straight from the accumulators -----
template<typename XIN, typename XOUT, bool STATS>
__global__ void __launch_bounds__(256,2) k_gemm(const XIN* __restrict__ xin,
    const ushort_t* __restrict__ WT, const float* __restrict__ qkg,
    float* __restrict__ sraw, const float* __restrict__ amS,
    const float* __restrict__ scale_a, XOUT* __restrict__ xout,
    float* __restrict__ pm, float* __restrict__ pS, float* __restrict__ pP){
  __shared__ __align__(16) ushort_t lA[CH*NC];
  __shared__ __align__(16) ushort_t lB[NC*NHD];
  __shared__ float sqk[256];
  __shared__ float shs0[CH], shs1[CH];
  __shared__ float red[8];
  __shared__ float pacc[4][2][NC];
  int wg = ((blockIdx.x & 7) * 196) + (blockIdx.x >> 3);
  int b = wg / PCH2, chunk = wg % PCH2;
  int l0 = chunk*CH;
  int t = threadIdx.x;
  float sa = scale_a[0]*0.5f;
  float am0 = amS[(b*2+0)*2+0], ai0 = amS[(b*2+0)*2+1];
  float am1 = amS[(b*2+1)*2+0], ai1 = amS[(b*2+1)*2+1];
  const float* s0p = sraw + ((size_t)b*2 + 0)*NL + l0;
  const float* s1p = sraw + ((size_t)b*2 + 1)*NL + l0;

  if (STATS){ sqk[t] = qkg[t]; }

  // stage B = WT[b] ([d][c]), swizzled
  {
    const ushort_t* src = WT + (size_t)b*NC*NHD;
    #pragma unroll
    for (int i = 0; i < 8; ++i){
      int idx = i*2048 + t*8;
      int d = idx >> 7;
      uint4 v = *(const uint4*)(src + idx);
      *(uint4*)((char*)lB + ((idx*2) ^ ((d & 7) << 4))) = v;
    }
  }
  // stage A = x*mod -> bf16, swizzled
  if constexpr (sizeof(XIN) == 4){
    const float* src = (const float*)xin + ((size_t)b*NL + l0)*NC;
    #pragma unroll
    for (int i = 0; i < 16; ++i){
      int idx = i*1024 + t*4;
      int row = idx >> 7;
      float4 v = *(const float4*)(src + idx);
      float mod = 1.f + sa*(__expf(s0p[row]-am0)*ai0 + __expf(s1p[row]-am1)*ai1);
      unsigned p0 = (unsigned)f2bf(v.x*mod) | ((unsigned)f2bf(v.y*mod) << 16);
      unsigned p1 = (unsigned)f2bf(v.z*mod) | ((unsigned)f2bf(v.w*mod) << 16);
      *(uint2*)((char*)lA + ((idx*2) ^ ((row & 7) << 4))) = make_uint2(p0, p1);
    }
  } else {
    const ushort_t* src = (const ushort_t*)xin + ((size_t)b*NL + l0)*NC;
    #pragma unroll
    for (int i = 0; i < 8; ++i){
      int idx = i*2048 + t*8;
      int row = idx >> 7;
      uint4 v = *(const uint4*)(src + idx);
      float mod = 1.f + sa*(__expf(s0p[row]-am0)*ai0 + __expf(s1p[row]-am1)*ai1);
      unsigned vv[4] = {v.x, v.y, v.z, v.w};
      unsigned r[4];
      #pragma unroll
      for (int j = 0; j < 4; ++j){
        float lo = bf2f(vv[j] & 0xffffu)*mod, hi2 = bf2f(vv[j] >> 16)*mod;
        r[j] = (unsigned)f2bf(lo) | ((unsigned)f2bf(hi2) << 16);
      }
      *(uint4*)((char*)lA + ((idx*2) ^ ((row & 7) << 4))) = make_uint4(r[0], r[1], r[2], r[3]);
    }
  }
  __syncthreads();

  int lane = t & 63, wave = t >> 6;
  int trow = lane & 15, kg = lane >> 4;
  int r0 = wave*32;
  f32x4 acc[2][8];
  #pragma unroll
  for (int m = 0; m < 2; ++m)
    #pragma unroll
    for (int n = 0; n < 8; ++n) acc[m][n] = (f32x4){0.f,0.f,0.f,0.f};

  #pragma unroll
  for (int kk = 0; kk < 4; ++kk){
    int k = kk*32 + kg*8;
    int ra0 = r0 + trow, ra1 = r0 + 16 + trow;
    bf16x8 a0 = *(const bf16x8*)((const char*)lA + ((ra0*256 + k*2) ^ ((ra0 & 7) << 4)));
    bf16x8 a1 = *(const bf16x8*)((const char*)lA + ((ra1*256 + k*2) ^ ((ra1 & 7) << 4)));
    #pragma unroll
    for (int nt = 0; nt < 8; ++nt){
      int col = nt*16 + trow;
      bf16x8 bf = *(const bf16x8*)((const char*)lB + ((col*256 + k*2) ^ ((col & 7) << 4)));
      acc[0][nt] = __builtin_amdgcn_mfma_f32_16x16x32_bf16(a0, bf, acc[0][nt], 0, 0, 0);
      acc[1][nt] = __builtin_amdgcn_mfma_f32_16x16x32_bf16(a1, bf, acc[1][nt], 0, 0, 0);
    }
  }

  // store C (fire-and-forget, overlaps epilogue)
  size_t base = ((size_t)b*NL + l0)*NC;
  #pragma unroll
  for (int m = 0; m < 2; ++m)
    #pragma unroll
    for (int nt = 0; nt < 8; ++nt)
      #pragma unroll
      for (int r = 0; r < 4; ++r){
        int row = r0 + m*16 + kg*4 + r;
        int col = nt*16 + trow;
        float v = acc[m][nt][r];
        if constexpr (sizeof(XOUT) == 4) ((float*)xout)[base + (size_t)row*NC + col] = v;
        else                             ((ushort_t*)xout)[base + (size_t)row*NC + col] = f2bf(v);
      }

  if (STATS){
    // per-lane col weights
    float wq0[8], wq1[8];
    #pragma unroll
    for (int nt = 0; nt < 8; ++nt){
      wq0[nt] = sqk[(nt*16 + trow)*2 + 0];
      wq1[nt] = sqk[(nt*16 + trow)*2 + 1];
    }
    // scores: reduce over cols (trow butterfly), scatter into shs
    #pragma unroll
    for (int m = 0; m < 2; ++m)
      #pragma unroll
      for (int r = 0; r < 4; ++r){
        float p0 = 0.f, p1 = 0.f;
        #pragma unroll
        for (int nt = 0; nt < 8; ++nt){ float v = acc[m][nt][r]; p0 += v*wq0[nt]; p1 += v*wq1[nt]; }
        #pragma unroll
        for (int mk = 1; mk < 16; mk <<= 1){ p0 += __shfl_xor(p0, mk); p1 += __shfl_xor(p1, mk); }
        int idx = m*4 + r;
        if (trow == idx){
          int row = r0 + m*16 + kg*4 + r;
          shs0[row] = p0; shs1[row] = p1;
        }
      }
    __syncthreads();

    // block softmax stats
    float s0 = -3.4e38f, s1 = -3.4e38f;
    if (t < 128){
      s0 = shs0[t]; s1 = shs1[t];
      sraw[((size_t)b*2+0)*NL + l0 + t] = s0;
      sraw[((size_t)b*2+1)*NL + l0 + t] = s1;
    }
    float m0 = s0, m1 = s1;
    #pragma unroll
    for (int mk = 32; mk; mk >>= 1){ m0 = fmaxf(m0, __shfl_xor(m0, mk)); m1 = fmaxf(m1, __shfl_xor(m1, mk)); }
    if (lane == 0 && wave < 2){ red[wave] = m0; red[2+wave] = m1; }
    __syncthreads();
    float M0 = fmaxf(red[0], red[1]), M1 = fmaxf(red[2], red[3]);
    float e0 = 0.f, e1 = 0.f;
    if (t < 128){ e0 = __expf(s0 - M0); e1 = __expf(s1 - M1); shs0[t] = e0; shs1[t] = e1; }
    float t0 = e0, t1 = e1;
    #pragma unroll
    for (int mk = 32; mk; mk >>= 1){ t0 += __shfl_xor(t0, mk); t1 += __shfl_xor(t1, mk); }
    if (lane == 0 && wave < 2){ red[4+wave] = t0; red[6+wave] = t1; }
    __syncthreads();
    if (t == 0){
      pm[(b*2+0)*PCH2 + chunk] = M0; pm[(b*2+1)*PCH2 + chunk] = M1;
      pS[(b*2+0)*PCH2 + chunk] = red[4]+red[5];
      pS[(b*2+1)*PCH2 + chunk] = red[6]+red[7];
    }

    // partial pooled from accumulators: P[h][col] = sum_row e_h[row]*acc[row][col]
    float ea0[2][4], ea1[2][4];
    #pragma unroll
    for (int m = 0; m < 2; ++m)
      #pragma unroll
      for (int r = 0; r < 4; ++r){
        int row = r0 + m*16 + kg*4 + r;
        ea0[m][r] = shs0[row]; ea1[m][r] = shs1[row];
      }
    #pragma unroll
    for (int nt = 0; nt < 8; ++nt){
      float p0 = 0.f, p1 = 0.f;
      #pragma unroll
      for (int m = 0; m < 2; ++m)
        #pragma unroll
        for (int r = 0; r < 4; ++r){
          p0 += ea0[m][r]*acc[m][nt][r];
          p1 += ea1[m][r]*acc[m][nt][r];
        }
      p0 += __shfl_xor(p0, 16); p0 += __shfl_xor(p0, 32);
      p1 += __shfl_xor(p1, 16); p1 += __shfl_xor(p1, 32);
      int col = nt*16 + trow;
      if (kg == 0) pacc[wave][0][col] = p0;
      if (kg == 1) pacc[wave][1][col] = p1;
    }
    __syncthreads();
    {
      int h = t >> 7, c = t & 127;
      pP[(((size_t)b*PCH2 + chunk)*2 + h)*NC + c] =
        pacc[0][h][c] + pacc[1][h][c] + pacc[2][h][c] + pacc[3][h][c];
    }
  }
}

extern "C" void kernel_launch(void* const* d_in, const int* in_sizes, int n_in,
                              void* d_out, int out_size, void* d_ws, size_t ws_size,
                              hipStream_t stream){
  const float* x0   = (const float*)d_in[0];
  const float* Wk   = (const float*)d_in[1];
  const float* Wv   = (const float*)d_in[2];
  const float* q    = (const float*)d_in[3];
  const float* Wmlp = (const float*)d_in[4];
  const float* Wb   = (const float*)d_in[5];
  const float* alpha= (const float*)d_in[6];
  float* out = (float*)d_out;

  char* ws = (char*)d_ws;
  float* qk      = (float*)ws;                        // 256 f (+pad)
  float* scale_a = qk + 256;
  float* sraw    = qk + 320;                          // B*2*L f
  float* pm      = sraw + (size_t)NB*2*NL;            // B*2*98 f
  float* pS      = pm + NB*2*PCH2;
  float* pP      = pS + NB*2*PCH2;                    // B*98*2*128 f
  float* amS     = pP + (size_t)NB*PCH2*2*NC;         // B*2*2 f
  ushort_t* WT   = (ushort_t*)(amS + NB*4);           // B*128*128 bf16
  char* endfixed = (char*)(WT + (size_t)NB*NC*NHD);
  size_t xoff    = ((size_t)(endfixed - ws) + 255) & ~(size_t)255;
  ushort_t* xb   = (ushort_t*)(ws + xoff);
  bool big = ws_size >= xoff + (size_t)ROWS*NC*2;

  k_prep<<<1, 256, 0, stream>>>(Wk, q, alpha, qk, scale_a);

  // step-0 router stats from x0
  k_pass1<<<NB*PCH2, 256, 0, stream>>>(x0, qk, sraw, pm, pS, pP);

  dim3 g(NB*PCH2);
  for (int step = 0; step < 3; ++step){
    k_combine<<<NB, 256, 0, stream>>>(pm, pS, pP, Wv, Wmlp, Wb, WT, amS);

    if (big){
      if (step == 0)
        k_gemm<float, ushort_t, true ><<<g, 256, 0, stream>>>(x0, WT, qk, sraw, amS, scale_a, xb, pm, pS, pP);
      else if (step == 1)
        k_gemm<ushort_t, ushort_t, true ><<<g, 256, 0, stream>>>(xb, WT, qk, sraw, amS, scale_a, xb, pm, pS, pP);
      else
        k_gemm<ushort_t, float, false><<<g, 256, 0, stream>>>(xb, WT, qk, sraw, amS, scale_a, out, pm, pS, pP);
    } else {
      if (step == 0)
        k_gemm<float, float, true ><<<g, 256, 0, stream>>>(x0, WT, qk, sraw, amS, scale_a, out, pm, pS, pP);
      else if (step == 1)
        k_gemm<float, float, true ><<<g, 256, 0, stream>>>(out, WT, qk, sraw, amS, scale_a, out, pm, pS, pP);
      else
        k_gemm<float, float, false><<<g, 256, 0, stream>>>(out, WT, qk, sraw, amS, scale_a, out, pm, pS, pP);
    }
  }
}